// Round 1
// baseline (168.161 us; speedup 1.0000x reference)
//
#include <hip/hip_runtime.h>
#include <hip/hip_bf16.h>

#define BSZ 8
#define T 2048
#define C 1024
#define H 64
#define M (BSZ*T)

typedef __attribute__((ext_vector_type(4))) float f32x4;
typedef __attribute__((ext_vector_type(8))) short bf16x8;
typedef __attribute__((ext_vector_type(4))) short s16x4;
typedef __attribute__((ext_vector_type(8))) short s16x8;

static __device__ __forceinline__ short f2bf(float f) {
  union { float f; unsigned u; } c; c.f = f;
  unsigned u = c.u;
  u = (u + 0x7fffu + ((u >> 16) & 1u)) >> 16;   // RNE, finite inputs only
  return (short)u;
}

// ---------------- Kernel 0: wt[w][h][c] (bf16) = W_w[c][h] ----------------
__global__ __launch_bounds__(256) void k_wt(const float* __restrict__ Wq,
                                            const float* __restrict__ Wk,
                                            const float* __restrict__ Wv,
                                            short* __restrict__ wt) {
  int idx = blockIdx.x * 256 + threadIdx.x;  // [0, 3*H*C)
  int c = idx & (C - 1);
  int n = idx >> 10;           // w*H + h
  int w = n >> 6;
  int h = n & (H - 1);
  const float* W = (w == 0) ? Wq : (w == 1) ? Wk : Wv;
  wt[idx] = f2bf(W[c * H + h]);
}

// ---------------- Kernel 1: fused QKV projection (bf16 MFMA) ----------------
// qb,kb: [M][H] bf16 row-major. vt: [BSZ][H][T] bf16 (V transposed per batch).
__global__ __launch_bounds__(256) void k_qkv(const float* __restrict__ x,
                                             const short* __restrict__ wt,
                                             short* __restrict__ qb,
                                             short* __restrict__ kb,
                                             short* __restrict__ vt) {
  __shared__ short xs[64][72];    // 64 rows x 64 k (bf16), pad to 72
  __shared__ short wl[192][72];   // 192 n-cols x 64 k (bf16), pad to 72
  const int tid = threadIdx.x;
  const int m0 = blockIdx.x * 64;
  const int lane = tid & 63;
  const int wv = tid >> 6;
  const int g16 = lane >> 4, l16 = lane & 15;

  f32x4 acc[12];
  #pragma unroll
  for (int i = 0; i < 12; ++i) acc[i] = (f32x4){0.f, 0.f, 0.f, 0.f};

  const int xc = (tid & 15) * 4;   // float col within chunk
  const int xr = tid >> 4;         // row base
  const int wc = (tid & 7) * 8;    // bf16 col within chunk
  const int wr = tid >> 3;         // n base

  for (int kc = 0; kc < C; kc += 64) {
    #pragma unroll
    for (int p = 0; p < 4; ++p) {
      int r = xr + p * 16;
      float4 f = *(const float4*)&x[(m0 + r) * C + kc + xc];
      s16x4 h4 = { f2bf(f.x), f2bf(f.y), f2bf(f.z), f2bf(f.w) };
      *(s16x4*)&xs[r][xc] = h4;
    }
    #pragma unroll
    for (int p = 0; p < 6; ++p) {
      int n = wr + p * 32;
      s16x8 v = *(const s16x8*)&wt[n * C + kc + wc];
      *(s16x8*)&wl[n][wc] = v;
    }
    __syncthreads();
    #pragma unroll
    for (int ks = 0; ks < 2; ++ks) {
      bf16x8 a = *(const bf16x8*)&xs[wv * 16 + l16][ks * 32 + g16 * 8];
      #pragma unroll
      for (int nt = 0; nt < 12; ++nt) {
        bf16x8 b = *(const bf16x8*)&wl[nt * 16 + l16][ks * 32 + g16 * 8];
        acc[nt] = __builtin_amdgcn_mfma_f32_16x16x32_bf16(a, b, acc[nt], 0, 0, 0);
      }
    }
    __syncthreads();
  }

  const int r0 = wv * 16 + g16 * 4;
  #pragma unroll
  for (int nt = 0; nt < 12; ++nt) {
    const int which = nt >> 2;               // 0=q 1=k 2=v
    const int h = (nt & 3) * 16 + l16;
    #pragma unroll
    for (int j = 0; j < 4; ++j) {
      const int tg = m0 + r0 + j;
      const short val = f2bf(acc[nt][j]);
      if (which == 0)      qb[tg * H + h] = val;
      else if (which == 1) kb[tg * H + h] = val;
      else {
        const int b = tg >> 11, tl = tg & (T - 1);
        vt[((b << 6) + h) * T + tl] = val;
      }
    }
  }
}

// ---------------- Kernel 2: flash attention w/ folded span ----------------
__global__ __launch_bounds__(64) void k_attn(const short* __restrict__ qb,
                                             const short* __restrict__ kb,
                                             const short* __restrict__ vt,
                                             const float* __restrict__ cvp,
                                             float* __restrict__ out) {
  __shared__ short plds[16][40];
  const int blk = blockIdx.x;
  const int b = blk >> 7;
  const int q0 = (127 - (blk & 127)) << 4;   // heavy tiles dispatched first
  const int lane = threadIdx.x;
  const int g16 = lane >> 4, l16 = lane & 15;
  const float cv = cvp[0];
  const float SCL = 0.125f * 1.44269504f;    // 1/sqrt(64) * log2(e)

  const short* qp = qb + ((b << 11) + q0 + l16) * H + g16 * 8;
  bf16x8 qf0 = *(const bf16x8*)qp;
  bf16x8 qf1 = *(const bf16x8*)(qp + 32);

  float m[4], L[4];
  f32x4 O[4];
  #pragma unroll
  for (int j = 0; j < 4; ++j) { m[j] = -3e38f; L[j] = 0.f; }
  #pragma unroll
  for (int t = 0; t < 4; ++t) O[t] = (f32x4){0.f, 0.f, 0.f, 0.f};

  const int nkv = q0 + 16;
  const int rowb = q0 + g16 * 4;

  for (int kv0 = 0; kv0 < nkv; kv0 += 32) {
    f32x4 s0 = {0.f,0.f,0.f,0.f}, s1 = {0.f,0.f,0.f,0.f};
    const short* kp = kb + ((b << 11) + kv0 + l16) * H + g16 * 8;
    bf16x8 kf0 = *(const bf16x8*)kp;
    bf16x8 kf1 = *(const bf16x8*)(kp + 32);
    s0 = __builtin_amdgcn_mfma_f32_16x16x32_bf16(qf0, kf0, s0, 0, 0, 0);
    s0 = __builtin_amdgcn_mfma_f32_16x16x32_bf16(qf1, kf1, s0, 0, 0, 0);
    kf0 = *(const bf16x8*)(kp + 16 * H);
    kf1 = *(const bf16x8*)(kp + 16 * H + 32);
    s1 = __builtin_amdgcn_mfma_f32_16x16x32_bf16(qf0, kf0, s1, 0, 0, 0);
    s1 = __builtin_amdgcn_mfma_f32_16x16x32_bf16(qf1, kf1, s1, 0, 0, 0);

    const int c0 = kv0 + l16, c1 = c0 + 16;
    float sv0[4], sv1[4], pm[4];
    #pragma unroll
    for (int j = 0; j < 4; ++j) {
      const int row = rowb + j;
      sv0[j] = (c0 <= row) ? s0[j] * SCL : -1e30f;
      sv1[j] = (c1 <= row) ? s1[j] * SCL : -1e30f;
      float v = fmaxf(sv0[j], sv1[j]);
      v = fmaxf(v, __shfl_xor(v, 1, 16));
      v = fmaxf(v, __shfl_xor(v, 2, 16));
      v = fmaxf(v, __shfl_xor(v, 4, 16));
      v = fmaxf(v, __shfl_xor(v, 8, 16));
      pm[j] = v;
    }
    const float sp0 = fminf(fmaxf((float)(c0 + 1) * (1.f / 2048.f) + cv, 0.f), 1.f);
    const float sp1 = fminf(fmaxf((float)(c1 + 1) * (1.f / 2048.f) + cv, 0.f), 1.f);
    float p0[4], p1[4], al[4];
    #pragma unroll
    for (int j = 0; j < 4; ++j) {
      const float mn = fmaxf(m[j], pm[j]);
      al[j] = exp2f(m[j] - mn);
      m[j] = mn;
      p0[j] = exp2f(sv0[j] - mn) * sp0;
      p1[j] = exp2f(sv1[j] - mn) * sp1;
      float rs = p0[j] + p1[j];
      rs += __shfl_xor(rs, 1, 16);
      rs += __shfl_xor(rs, 2, 16);
      rs += __shfl_xor(rs, 4, 16);
      rs += __shfl_xor(rs, 8, 16);
      L[j] = L[j] * al[j] + rs;
    }
    #pragma unroll
    for (int t = 0; t < 4; ++t)
      #pragma unroll
      for (int j = 0; j < 4; ++j) O[t][j] *= al[j];

    __syncthreads();   // WAR: prior pa read done before overwrite
    #pragma unroll
    for (int j = 0; j < 4; ++j) {
      plds[g16 * 4 + j][l16]      = f2bf(p0[j]);
      plds[g16 * 4 + j][16 + l16] = f2bf(p1[j]);
    }
    __syncthreads();
    bf16x8 pa = *(const bf16x8*)&plds[l16][g16 * 8];
    #pragma unroll
    for (int t = 0; t < 4; ++t) {
      const short* vp = vt + ((b << 6) + t * 16 + l16) * T + kv0 + g16 * 8;
      bf16x8 vf = *(const bf16x8*)vp;
      O[t] = __builtin_amdgcn_mfma_f32_16x16x32_bf16(pa, vf, O[t], 0, 0, 0);
    }
  }

  #pragma unroll
  for (int t = 0; t < 4; ++t) {
    #pragma unroll
    for (int j = 0; j < 4; ++j) {
      out[((b << 11) + rowb + j) * H + t * 16 + l16] = O[t][j] / L[j];
    }
  }
}

extern "C" void kernel_launch(void* const* d_in, const int* in_sizes, int n_in,
                              void* d_out, int out_size, void* d_ws, size_t ws_size,
                              hipStream_t stream) {
  const float* x  = (const float*)d_in[0];
  const float* Wq = (const float*)d_in[1];
  const float* Wk = (const float*)d_in[2];
  const float* Wv = (const float*)d_in[3];
  const float* cv = (const float*)d_in[4];
  float* out = (float*)d_out;

  char* ws = (char*)d_ws;
  short* qb = (short*)(ws);                              // 2 MB
  short* kb = (short*)(ws + (size_t)M * H * 2);          // 2 MB
  short* vt = (short*)(ws + (size_t)2 * M * H * 2);      // 2 MB
  short* wt = (short*)(ws + (size_t)3 * M * H * 2);      // 384 KB

  hipLaunchKernelGGL(k_wt, dim3(3 * H * C / 256), dim3(256), 0, stream, Wq, Wk, Wv, wt);
  hipLaunchKernelGGL(k_qkv, dim3(M / 64), dim3(256), 0, stream, x, wt, qb, kb, vt);
  hipLaunchKernelGGL(k_attn, dim3(BSZ * T / 16), dim3(64), 0, stream, qb, kb, vt, cv, out);
}

// Round 2
// 120.179 us; speedup vs baseline: 1.3993x; 1.3993x over previous
//
#include <hip/hip_runtime.h>
#include <hip/hip_bf16.h>

#define BSZ 8
#define T 2048
#define C 1024
#define H 64
#define M (BSZ*T)

typedef __attribute__((ext_vector_type(4))) float f32x4;
typedef __attribute__((ext_vector_type(8))) short bf16x8;
typedef __attribute__((ext_vector_type(4))) short s16x4;
typedef __attribute__((ext_vector_type(8))) short s16x8;

static __device__ __forceinline__ short f2bf(float f) {
  union { float f; unsigned u; } c; c.f = f;
  unsigned u = c.u;
  u = (u + 0x7fffu + ((u >> 16) & 1u)) >> 16;   // RNE, finite inputs only
  return (short)u;
}

// ---------------- Kernel 0: wt[w][h][c] (bf16) = W_w[c][h] ----------------
__global__ __launch_bounds__(256) void k_wt(const float* __restrict__ Wq,
                                            const float* __restrict__ Wk,
                                            const float* __restrict__ Wv,
                                            short* __restrict__ wt) {
  int idx = blockIdx.x * 256 + threadIdx.x;  // [0, 3*H*C)
  int c = idx & (C - 1);
  int n = idx >> 10;           // w*H + h
  int w = n >> 6;
  int h = n & (H - 1);
  const float* W = (w == 0) ? Wq : (w == 1) ? Wk : Wv;
  wt[idx] = f2bf(W[c * H + h]);
}

// ---------------- Kernel 1: fused QKV projection (bf16 MFMA) ----------------
// M-tile 32, 512 blocks (2/CU). qb,kb: [M][H] bf16. vt: [BSZ][H][T] bf16.
__global__ __launch_bounds__(256) void k_qkv(const float* __restrict__ x,
                                             const short* __restrict__ wt,
                                             short* __restrict__ qb,
                                             short* __restrict__ kb,
                                             short* __restrict__ vt) {
  __shared__ short xs[32][72];    // 32 rows x 64 k (bf16), pad to 72
  __shared__ short wl[192][72];   // 192 n-cols x 64 k (bf16), pad to 72
  const int tid = threadIdx.x;
  const int m0 = blockIdx.x * 32;
  const int lane = tid & 63;
  const int wid = tid >> 6;
  const int g16 = lane >> 4, l16 = lane & 15;
  const int row0 = (wid & 1) * 16;      // wave's 16 rows within tile
  const int nc0 = (wid >> 1) * 96;      // wave's 96 output cols

  f32x4 acc[6];
  #pragma unroll
  for (int i = 0; i < 6; ++i) acc[i] = (f32x4){0.f, 0.f, 0.f, 0.f};

  const int xc = (tid & 15) * 4;   // float col within chunk
  const int xr = tid >> 4;         // 0..15
  const int wc = (tid & 7) * 8;    // bf16 col within chunk
  const int wr = tid >> 3;         // 0..31

  for (int kc = 0; kc < C; kc += 64) {
    #pragma unroll
    for (int p = 0; p < 2; ++p) {
      int r = xr + p * 16;
      float4 f = *(const float4*)&x[(size_t)(m0 + r) * C + kc + xc];
      s16x4 h4 = { f2bf(f.x), f2bf(f.y), f2bf(f.z), f2bf(f.w) };
      *(s16x4*)&xs[r][xc] = h4;
    }
    #pragma unroll
    for (int p = 0; p < 6; ++p) {
      int n = wr + p * 32;
      *(s16x8*)&wl[n][wc] = *(const s16x8*)&wt[n * C + kc + wc];
    }
    __syncthreads();
    #pragma unroll
    for (int ks = 0; ks < 2; ++ks) {
      bf16x8 a = *(const bf16x8*)&xs[row0 + l16][ks * 32 + g16 * 8];
      #pragma unroll
      for (int nt = 0; nt < 6; ++nt) {
        bf16x8 bfr = *(const bf16x8*)&wl[nc0 + nt * 16 + l16][ks * 32 + g16 * 8];
        acc[nt] = __builtin_amdgcn_mfma_f32_16x16x32_bf16(a, bfr, acc[nt], 0, 0, 0);
      }
    }
    __syncthreads();
  }

  const int r0 = row0 + g16 * 4;
  #pragma unroll
  for (int nt = 0; nt < 6; ++nt) {
    const int nglob = nc0 + nt * 16;
    const int which = nglob >> 6;            // 0=q 1=k 2=v
    const int col = (nglob & 63) + l16;
    #pragma unroll
    for (int j = 0; j < 4; ++j) {
      const int tg = m0 + r0 + j;
      const short val = f2bf(acc[nt][j]);
      if (which == 0)      qb[tg * H + col] = val;
      else if (which == 1) kb[tg * H + col] = val;
      else {
        const int b = tg >> 11, tl = tg & (T - 1);
        vt[((b << 6) + col) * T + tl] = val;
      }
    }
  }
}

// ---------------- Kernel 2: flash attention, 4-wave KV-split ----------------
// Block = 4 waves; each wave covers a contiguous 1/4 of the tile's KV range,
// accumulating private (m, L, O); merged at block end via LDS.
__global__ __launch_bounds__(256) void k_attn(const short* __restrict__ qb,
                                              const short* __restrict__ kb,
                                              const short* __restrict__ vt,
                                              const float* __restrict__ cvp,
                                              float* __restrict__ out) {
  __shared__ short plds[4][2][16][40];   // per-wave, double-buffered P tile
  __shared__ float mw[4][16];
  __shared__ float Lw[4][16];
  __shared__ float Ow[4][16][68];        // pad 68 to spread banks
  const int blk = blockIdx.x;
  const int b = blk >> 7;
  const int t = 127 - (blk & 127);       // heavy tiles dispatched first
  const int q0 = t << 4;
  const int tid = threadIdx.x;
  const int wid = tid >> 6;
  const int lane = tid & 63;
  const int g16 = lane >> 4, l16 = lane & 15;
  const float cv = cvp[0];
  const float SCL = 0.125f * 1.44269504f;    // 1/sqrt(64) * log2(e)

  const int nit = (q0 + 16 + 31) >> 5;   // total 32-col iterations (causal)
  const int npw = (nit + 3) >> 2;
  const int lo = wid * npw;
  const int hi = (lo + npw < nit) ? lo + npw : nit;

  const short* qp = qb + ((b << 11) + q0 + l16) * H + g16 * 8;
  bf16x8 qf0 = *(const bf16x8*)qp;
  bf16x8 qf1 = *(const bf16x8*)(qp + 32);

  float m[4], L[4];
  f32x4 O[4];
  #pragma unroll
  for (int j = 0; j < 4; ++j) { m[j] = -3e38f; L[j] = 0.f; }
  #pragma unroll
  for (int tt = 0; tt < 4; ++tt) O[tt] = (f32x4){0.f, 0.f, 0.f, 0.f};

  const int rowb = q0 + g16 * 4;

  for (int it = lo; it < hi; ++it) {
    const int kv0 = it << 5;
    f32x4 s0 = {0.f,0.f,0.f,0.f}, s1 = {0.f,0.f,0.f,0.f};
    const short* kp = kb + ((b << 11) + kv0 + l16) * H + g16 * 8;
    bf16x8 kf0 = *(const bf16x8*)kp;
    bf16x8 kf1 = *(const bf16x8*)(kp + 32);
    s0 = __builtin_amdgcn_mfma_f32_16x16x32_bf16(qf0, kf0, s0, 0, 0, 0);
    s0 = __builtin_amdgcn_mfma_f32_16x16x32_bf16(qf1, kf1, s0, 0, 0, 0);
    kf0 = *(const bf16x8*)(kp + 16 * H);
    kf1 = *(const bf16x8*)(kp + 16 * H + 32);
    s1 = __builtin_amdgcn_mfma_f32_16x16x32_bf16(qf0, kf0, s1, 0, 0, 0);
    s1 = __builtin_amdgcn_mfma_f32_16x16x32_bf16(qf1, kf1, s1, 0, 0, 0);

    const int c0 = kv0 + l16, c1 = c0 + 16;
    float sv0[4], sv1[4], pm[4];
    #pragma unroll
    for (int j = 0; j < 4; ++j) {
      const int row = rowb + j;
      sv0[j] = (c0 <= row) ? s0[j] * SCL : -1e30f;
      sv1[j] = (c1 <= row) ? s1[j] * SCL : -1e30f;
      float v = fmaxf(sv0[j], sv1[j]);
      v = fmaxf(v, __shfl_xor(v, 1, 16));
      v = fmaxf(v, __shfl_xor(v, 2, 16));
      v = fmaxf(v, __shfl_xor(v, 4, 16));
      v = fmaxf(v, __shfl_xor(v, 8, 16));
      pm[j] = v;
    }
    const float sp0 = fminf(fmaxf((float)(c0 + 1) * (1.f / 2048.f) + cv, 0.f), 1.f);
    const float sp1 = fminf(fmaxf((float)(c1 + 1) * (1.f / 2048.f) + cv, 0.f), 1.f);
    float p0[4], p1[4], al[4];
    #pragma unroll
    for (int j = 0; j < 4; ++j) {
      const float mn = fmaxf(m[j], pm[j]);
      al[j] = exp2f(m[j] - mn);
      m[j] = mn;
      p0[j] = exp2f(sv0[j] - mn) * sp0;
      p1[j] = exp2f(sv1[j] - mn) * sp1;
      float rs = p0[j] + p1[j];
      rs += __shfl_xor(rs, 1, 16);
      rs += __shfl_xor(rs, 2, 16);
      rs += __shfl_xor(rs, 4, 16);
      rs += __shfl_xor(rs, 8, 16);
      L[j] = L[j] * al[j] + rs;
    }
    #pragma unroll
    for (int tt = 0; tt < 4; ++tt)
      #pragma unroll
      for (int j = 0; j < 4; ++j) O[tt][j] *= al[j];

    short (*pl)[40] = plds[wid][it & 1];
    #pragma unroll
    for (int j = 0; j < 4; ++j) {
      pl[g16 * 4 + j][l16]      = f2bf(p0[j]);
      pl[g16 * 4 + j][16 + l16] = f2bf(p1[j]);
    }
    bf16x8 pa = *(const bf16x8*)&pl[l16][g16 * 8];
    #pragma unroll
    for (int tt = 0; tt < 4; ++tt) {
      const short* vp = vt + ((b << 6) + tt * 16 + l16) * T + kv0 + g16 * 8;
      bf16x8 vf = *(const bf16x8*)vp;
      O[tt] = __builtin_amdgcn_mfma_f32_16x16x32_bf16(pa, vf, O[tt], 0, 0, 0);
    }
  }

  // ---- write per-wave partials ----
  #pragma unroll
  for (int j = 0; j < 4; ++j) {
    if (l16 == 0) {
      mw[wid][g16 * 4 + j] = m[j];
      Lw[wid][g16 * 4 + j] = L[j];
    }
  }
  #pragma unroll
  for (int tt = 0; tt < 4; ++tt)
    #pragma unroll
    for (int j = 0; j < 4; ++j)
      Ow[wid][g16 * 4 + j][tt * 16 + l16] = O[tt][j];
  __syncthreads();

  // ---- merge 4 partials: thread -> (row, 4 cols) ----
  {
    const int r = tid >> 4;
    const int c4 = (tid & 15) << 2;
    float m0 = mw[0][r], m1 = mw[1][r], m2 = mw[2][r], m3 = mw[3][r];
    float Mx = fmaxf(fmaxf(m0, m1), fmaxf(m2, m3));
    float f0 = exp2f(m0 - Mx), f1 = exp2f(m1 - Mx);
    float f2 = exp2f(m2 - Mx), f3 = exp2f(m3 - Mx);
    float Ls = Lw[0][r] * f0 + Lw[1][r] * f1 + Lw[2][r] * f2 + Lw[3][r] * f3;
    f32x4 o0 = *(const f32x4*)&Ow[0][r][c4];
    f32x4 o1 = *(const f32x4*)&Ow[1][r][c4];
    f32x4 o2 = *(const f32x4*)&Ow[2][r][c4];
    f32x4 o3 = *(const f32x4*)&Ow[3][r][c4];
    f32x4 o = o0 * f0 + o1 * f1 + o2 * f2 + o3 * f3;
    const float inv = 1.f / (Ls + 1e-30f);
    o *= inv;
    *(f32x4*)&out[(size_t)((b << 11) + q0 + r) * H + c4] = o;
  }
}

extern "C" void kernel_launch(void* const* d_in, const int* in_sizes, int n_in,
                              void* d_out, int out_size, void* d_ws, size_t ws_size,
                              hipStream_t stream) {
  const float* x  = (const float*)d_in[0];
  const float* Wq = (const float*)d_in[1];
  const float* Wk = (const float*)d_in[2];
  const float* Wv = (const float*)d_in[3];
  const float* cv = (const float*)d_in[4];
  float* out = (float*)d_out;

  char* ws = (char*)d_ws;
  short* qb = (short*)(ws);                              // 2 MB
  short* kb = (short*)(ws + (size_t)M * H * 2);          // 2 MB
  short* vt = (short*)(ws + (size_t)2 * M * H * 2);      // 2 MB
  short* wt = (short*)(ws + (size_t)3 * M * H * 2);      // 384 KB

  hipLaunchKernelGGL(k_wt, dim3(3 * H * C / 256), dim3(256), 0, stream, Wq, Wk, Wv, wt);
  hipLaunchKernelGGL(k_qkv, dim3(M / 32), dim3(256), 0, stream, x, wt, qb, kb, vt);
  hipLaunchKernelGGL(k_attn, dim3(BSZ * T / 16), dim3(256), 0, stream, qb, kb, vt, cv, out);
}

// Round 3
// 88.188 us; speedup vs baseline: 1.9068x; 1.3628x over previous
//
#include <hip/hip_runtime.h>
#include <hip/hip_bf16.h>

#define BSZ 8
#define T 2048
#define C 1024
#define H 64
#define M (BSZ*T)

typedef __attribute__((ext_vector_type(4))) float f32x4;
typedef __attribute__((ext_vector_type(8))) short bf16x8;
typedef __attribute__((ext_vector_type(4))) short s16x4;
typedef __attribute__((ext_vector_type(8))) short s16x8;

static __device__ __forceinline__ short f2bf(float f) {
  union { float f; unsigned u; } c; c.f = f;
  unsigned u = c.u;
  u = (u + 0x7fffu + ((u >> 16) & 1u)) >> 16;   // RNE, finite inputs only
  return (short)u;
}

// ---------------- Kernel 0: wt[w][h][c] (bf16) = W_w[c][h] ----------------
__global__ __launch_bounds__(256) void k_wt(const float* __restrict__ Wq,
                                            const float* __restrict__ Wk,
                                            const float* __restrict__ Wv,
                                            short* __restrict__ wt) {
  int idx = blockIdx.x * 256 + threadIdx.x;  // [0, 3*H*C)
  int c = idx & (C - 1);
  int n = idx >> 10;           // w*H + h
  int w = n >> 6;
  int h = n & (H - 1);
  const float* W = (w == 0) ? Wq : (w == 1) ? Wk : Wv;
  wt[idx] = f2bf(W[c * H + h]);
}

// ---------------- Kernel 1: fused QKV projection, double-buffered ----------
// M-tile 32, 4 waves (2 row-groups x 2 col-groups of 96). LDS stride 64 with
// XOR swizzle col ^ ((row&7)<<3) -> per-thread-constant, conflict-free.
__global__ __launch_bounds__(256) void k_qkv(const float* __restrict__ x,
                                             const short* __restrict__ wt,
                                             short* __restrict__ qb,
                                             short* __restrict__ kb,
                                             short* __restrict__ vt) {
  __shared__ short xs[2][32 * 64];
  __shared__ short wl[2][192 * 64];
  const int tid = threadIdx.x;
  const int m0 = blockIdx.x * 32;
  const int lane = tid & 63;
  const int wid = tid >> 6;             // 0..3
  const int g16 = lane >> 4, l16 = lane & 15;
  const int row0 = (wid & 1) * 16;      // wave's 16 rows
  const int nc0 = (wid >> 1) * 96;      // wave's 96 output cols

  f32x4 acc[6];
  #pragma unroll
  for (int i = 0; i < 6; ++i) acc[i] = (f32x4){0.f, 0.f, 0.f, 0.f};

  const int xr = tid >> 4;              // 0..15
  const int xc4 = (tid & 15) * 4;       // 4-float / 4-short chunk
  const int xsw = xc4 ^ ((xr & 7) << 3);
  const int wr = tid >> 3;              // 0..31
  const int wc8 = (tid & 7) * 8;        // 8-short chunk
  const int wsw = wc8 ^ ((wr & 7) << 3);
  const int fsw = (l16 & 7) << 3;       // fragment-read swizzle (row = ..+l16)

  float4 xg0, xg1;
  s16x8 wg0, wg1, wg2, wg3, wg4, wg5;

#define QKV_LOAD(kc) do { \
    xg0 = *(const float4*)&x[(size_t)(m0 + xr) * C + (kc) + xc4]; \
    xg1 = *(const float4*)&x[(size_t)(m0 + xr + 16) * C + (kc) + xc4]; \
    wg0 = *(const s16x8*)&wt[(wr +   0) * C + (kc) + wc8]; \
    wg1 = *(const s16x8*)&wt[(wr +  32) * C + (kc) + wc8]; \
    wg2 = *(const s16x8*)&wt[(wr +  64) * C + (kc) + wc8]; \
    wg3 = *(const s16x8*)&wt[(wr +  96) * C + (kc) + wc8]; \
    wg4 = *(const s16x8*)&wt[(wr + 128) * C + (kc) + wc8]; \
    wg5 = *(const s16x8*)&wt[(wr + 160) * C + (kc) + wc8]; \
  } while (0)

#define QKV_STORE(buf) do { \
    s16x4 h0 = { f2bf(xg0.x), f2bf(xg0.y), f2bf(xg0.z), f2bf(xg0.w) }; \
    s16x4 h1 = { f2bf(xg1.x), f2bf(xg1.y), f2bf(xg1.z), f2bf(xg1.w) }; \
    *(s16x4*)&xs[buf][xr * 64 + xsw] = h0; \
    *(s16x4*)&xs[buf][(xr + 16) * 64 + xsw] = h1; \
    *(s16x8*)&wl[buf][(wr +   0) * 64 + wsw] = wg0; \
    *(s16x8*)&wl[buf][(wr +  32) * 64 + wsw] = wg1; \
    *(s16x8*)&wl[buf][(wr +  64) * 64 + wsw] = wg2; \
    *(s16x8*)&wl[buf][(wr +  96) * 64 + wsw] = wg3; \
    *(s16x8*)&wl[buf][(wr + 128) * 64 + wsw] = wg4; \
    *(s16x8*)&wl[buf][(wr + 160) * 64 + wsw] = wg5; \
  } while (0)

  QKV_LOAD(0);
  QKV_STORE(0);
  __syncthreads();

  int cur = 0;
  for (int it = 0; it < 16; ++it) {
    if (it < 15) QKV_LOAD((it + 1) * 64);
    #pragma unroll
    for (int ks = 0; ks < 2; ++ks) {
      bf16x8 a = *(const bf16x8*)&xs[cur][(row0 + l16) * 64 + ((ks * 32 + g16 * 8) ^ fsw)];
      #pragma unroll
      for (int nt = 0; nt < 6; ++nt) {
        bf16x8 bfr = *(const bf16x8*)&wl[cur][(nc0 + nt * 16 + l16) * 64 + ((ks * 32 + g16 * 8) ^ fsw)];
        acc[nt] = __builtin_amdgcn_mfma_f32_16x16x32_bf16(a, bfr, acc[nt], 0, 0, 0);
      }
    }
    if (it < 15) {
      QKV_STORE(cur ^ 1);   // prior reads of cur^1 finished before last barrier
      __syncthreads();
      cur ^= 1;
    }
  }
#undef QKV_LOAD
#undef QKV_STORE

  const int r0 = row0 + g16 * 4;
  #pragma unroll
  for (int nt = 0; nt < 6; ++nt) {
    const int nglob = nc0 + nt * 16;
    const int which = nglob >> 6;            // 0=q 1=k 2=v
    const int col = (nglob & 63) + l16;
    #pragma unroll
    for (int j = 0; j < 4; ++j) {
      const int tg = m0 + r0 + j;
      const short val = f2bf(acc[nt][j]);
      if (which == 0)      qb[tg * H + col] = val;
      else if (which == 1) kb[tg * H + col] = val;
      else {
        const int b = tg >> 11, tl = tg & (T - 1);
        vt[((b << 6) + col) * T + tl] = val;
      }
    }
  }
}

// ---------------- Kernel 2: flash attention, swapped operands --------------
// S = mfma(K, Q): lane l16 = q-col, regs = kv rows -> softmax is lane-local
// (in-register tree + xor16/xor32). PV also swapped: O = mfma(V^T, P), so O,
// m, L all stay indexed by q = l16. P goes through a tiny per-wave LDS tile.
__global__ __launch_bounds__(256) void k_attn(const short* __restrict__ qb,
                                              const short* __restrict__ kb,
                                              const short* __restrict__ vt,
                                              const float* __restrict__ cvp,
                                              float* __restrict__ out) {
  __shared__ short plds[4][2][16][40];
  __shared__ float mw[4][16];
  __shared__ float Lw[4][16];
  __shared__ float Ow[4][16][68];
  const int blk = blockIdx.x;
  const int b = blk >> 7;
  const int t = 127 - (blk & 127);       // heavy tiles dispatched first
  const int q0 = t << 4;
  const int tid = threadIdx.x;
  const int wid = tid >> 6;
  const int lane = tid & 63;
  const int g16 = lane >> 4, l16 = lane & 15;
  const float cv = cvp[0];
  const float SCL = 0.125f * 1.44269504f;    // 1/sqrt(64) * log2(e)

  const int nit = (q0 + 16 + 31) >> 5;   // 32-col iterations (causal)
  const int npw = (nit + 3) >> 2;
  const int lo = wid * npw;
  const int hi = (lo + npw < nit) ? lo + npw : nit;

  // Q as B-operand: B[k=h][col=q] -> qb[q0+l16][g16*8+j]
  const short* qp = qb + ((size_t)(b << 11) + q0 + l16) * H + g16 * 8;
  bf16x8 qf0 = *(const bf16x8*)qp;
  bf16x8 qf1 = *(const bf16x8*)(qp + 32);

  const int qg = q0 + l16;               // this lane's q row

  float m = -3e38f, L = 0.f;
  f32x4 O[4];
  #pragma unroll
  for (int t4 = 0; t4 < 4; ++t4) O[t4] = (f32x4){0.f, 0.f, 0.f, 0.f};

  for (int it = lo; it < hi; ++it) {
    const int kv0 = it << 5;
    // K as A-operand: A[row=kv][k=h] -> kb[kv0+tt*16+l16][g16*8+j]
    const short* kp = kb + ((size_t)(b << 11) + kv0 + l16) * H + g16 * 8;
    bf16x8 ka0 = *(const bf16x8*)kp;
    bf16x8 ka1 = *(const bf16x8*)(kp + 32);
    bf16x8 kb0 = *(const bf16x8*)(kp + 16 * H);
    bf16x8 kb1 = *(const bf16x8*)(kp + 16 * H + 32);
    f32x4 s0 = {0.f,0.f,0.f,0.f}, s1 = {0.f,0.f,0.f,0.f};
    s0 = __builtin_amdgcn_mfma_f32_16x16x32_bf16(ka0, qf0, s0, 0, 0, 0);
    s0 = __builtin_amdgcn_mfma_f32_16x16x32_bf16(ka1, qf1, s0, 0, 0, 0);
    s1 = __builtin_amdgcn_mfma_f32_16x16x32_bf16(kb0, qf0, s1, 0, 0, 0);
    s1 = __builtin_amdgcn_mfma_f32_16x16x32_bf16(kb1, qf1, s1, 0, 0, 0);

    // lane holds S[kv = kv0 + (r>>2)*16 + g16*4 + (r&3)][q = qg]
    const int kvb = kv0 + g16 * 4;
    float sv[8], sp[8];
    #pragma unroll
    for (int r = 0; r < 8; ++r) {
      const int kvg = kvb + ((r >> 2) << 4) + (r & 3);
      const float s = ((r < 4) ? s0[r] : s1[r - 4]) * SCL;
      sv[r] = (kvg <= qg) ? s : -1e30f;
      sp[r] = fminf(fmaxf((float)(kvg + 1) * (1.f / 2048.f) + cv, 0.f), 1.f);
    }
    float v = fmaxf(fmaxf(fmaxf(sv[0], sv[1]), fmaxf(sv[2], sv[3])),
                    fmaxf(fmaxf(sv[4], sv[5]), fmaxf(sv[6], sv[7])));
    v = fmaxf(v, __shfl_xor(v, 16, 64));
    v = fmaxf(v, __shfl_xor(v, 32, 64));
    const float mn = fmaxf(m, v);
    const float al = exp2f(m - mn);
    m = mn;
    float p[8];
    #pragma unroll
    for (int r = 0; r < 8; ++r) p[r] = exp2f(sv[r] - mn) * sp[r];
    float rs = ((p[0] + p[1]) + (p[2] + p[3])) + ((p[4] + p[5]) + (p[6] + p[7]));
    rs += __shfl_xor(rs, 16, 64);
    rs += __shfl_xor(rs, 32, 64);
    L = L * al + rs;
    #pragma unroll
    for (int t4 = 0; t4 < 4; ++t4) O[t4] *= al;

    // P -> LDS in PV B-layout: pl[q][kv_local], packed bf16 pairs (RTZ)
    short (*pl)[40] = plds[wid][it & 1];
    #pragma unroll
    for (int r = 0; r < 8; r += 2) {
      union { float f; unsigned u; } a0, a1;
      a0.f = p[r]; a1.f = p[r + 1];
      const unsigned pk = (a0.u >> 16) | (a1.u & 0xffff0000u);
      *(unsigned*)&pl[l16][((r >> 2) << 4) + g16 * 4 + (r & 3)] = pk;
    }
    // B-frag: col=q=l16, k=kv=g16*8+j
    bf16x8 pa = *(const bf16x8*)&pl[l16][g16 * 8];
    #pragma unroll
    for (int t4 = 0; t4 < 4; ++t4) {
      // V^T as A-operand: A[row=h][k=kv] -> vt[(b,h=t4*16+l16)][kv0+g16*8+j]
      const short* vp = vt + ((size_t)(b << 6) + t4 * 16 + l16) * T + kv0 + g16 * 8;
      bf16x8 vf = *(const bf16x8*)vp;
      O[t4] = __builtin_amdgcn_mfma_f32_16x16x32_bf16(vf, pa, O[t4], 0, 0, 0);
    }
  }

  // ---- per-wave partials: O[t4][j] = out[q=l16][h=t4*16+g16*4+j] ----
  if (g16 == 0) { mw[wid][l16] = m; Lw[wid][l16] = L; }
  #pragma unroll
  for (int t4 = 0; t4 < 4; ++t4)
    *(f32x4*)&Ow[wid][l16][t4 * 16 + g16 * 4] = O[t4];
  __syncthreads();

  // ---- merge 4 partials: thread -> (row, 4 cols) ----
  {
    const int r = tid >> 4;
    const int c4 = (tid & 15) << 2;
    float m0 = mw[0][r], m1 = mw[1][r], m2 = mw[2][r], m3 = mw[3][r];
    float Mx = fmaxf(fmaxf(m0, m1), fmaxf(m2, m3));
    float f0 = exp2f(m0 - Mx), f1 = exp2f(m1 - Mx);
    float f2 = exp2f(m2 - Mx), f3 = exp2f(m3 - Mx);
    float Ls = Lw[0][r] * f0 + Lw[1][r] * f1 + Lw[2][r] * f2 + Lw[3][r] * f3;
    f32x4 o0 = *(const f32x4*)&Ow[0][r][c4];
    f32x4 o1 = *(const f32x4*)&Ow[1][r][c4];
    f32x4 o2 = *(const f32x4*)&Ow[2][r][c4];
    f32x4 o3 = *(const f32x4*)&Ow[3][r][c4];
    f32x4 o = o0 * f0 + o1 * f1 + o2 * f2 + o3 * f3;
    const float inv = 1.f / (Ls + 1e-30f);
    o *= inv;
    *(f32x4*)&out[(size_t)((b << 11) + q0 + r) * H + c4] = o;
  }
}

extern "C" void kernel_launch(void* const* d_in, const int* in_sizes, int n_in,
                              void* d_out, int out_size, void* d_ws, size_t ws_size,
                              hipStream_t stream) {
  const float* x  = (const float*)d_in[0];
  const float* Wq = (const float*)d_in[1];
  const float* Wk = (const float*)d_in[2];
  const float* Wv = (const float*)d_in[3];
  const float* cv = (const float*)d_in[4];
  float* out = (float*)d_out;

  char* ws = (char*)d_ws;
  short* qb = (short*)(ws);                              // 2 MB
  short* kb = (short*)(ws + (size_t)M * H * 2);          // 2 MB
  short* vt = (short*)(ws + (size_t)2 * M * H * 2);      // 2 MB
  short* wt = (short*)(ws + (size_t)3 * M * H * 2);      // 384 KB

  hipLaunchKernelGGL(k_wt, dim3(3 * H * C / 256), dim3(256), 0, stream, Wq, Wk, Wv, wt);
  hipLaunchKernelGGL(k_qkv, dim3(M / 32), dim3(256), 0, stream, x, wt, qb, kb, vt);
  hipLaunchKernelGGL(k_attn, dim3(BSZ * T / 16), dim3(256), 0, stream, qb, kb, vt, cv, out);
}

// Round 5
// 65.907 us; speedup vs baseline: 2.5515x; 1.3381x over previous
//
#include <hip/hip_runtime.h>
#include <hip/hip_bf16.h>

#define BSZ 8
#define T 2048
#define C 1024
#define H 64
#define M (BSZ*T)

typedef __attribute__((ext_vector_type(4))) float f32x4;
typedef __attribute__((ext_vector_type(8))) short bf16x8;
typedef __attribute__((ext_vector_type(4))) short s16x4;
typedef __attribute__((ext_vector_type(8))) short s16x8;

static __device__ __forceinline__ short f2bf(float f) {
  union { float f; unsigned u; } c; c.f = f;
  unsigned u = c.u;
  u = (u + 0x7fffu + ((u >> 16) & 1u)) >> 16;   // RNE, finite inputs only
  return (short)u;
}

// ---------------- Kernel 0: wt[w][h][c] (bf16) = W_w[c][h] ----------------
__global__ __launch_bounds__(256) void k_wt(const float* __restrict__ Wq,
                                            const float* __restrict__ Wk,
                                            const float* __restrict__ Wv,
                                            short* __restrict__ wt) {
  int idx = blockIdx.x * 256 + threadIdx.x;  // [0, 3*H*C)
  int c = idx & (C - 1);
  int n = idx >> 10;           // w*H + h
  int w = n >> 6;
  int h = n & (H - 1);
  const float* W = (w == 0) ? Wq : (w == 1) ? Wk : Wv;
  wt[idx] = f2bf(W[c * H + h]);
}

// ---------------- Kernel 1: fused QKV projection, 2-deep pipeline ----------
// M-tile 32, 4 waves. LDS stride 64 with XOR swizzle col ^ ((row&7)<<3).
// Loads issued 2 iterations ahead (reg sets A/B), so the ds_write's vmcnt
// wait is covered by a full iteration (~HBM latency).
__global__ __launch_bounds__(256) void k_qkv(const float* __restrict__ x,
                                             const short* __restrict__ wt,
                                             short* __restrict__ qb,
                                             short* __restrict__ kb,
                                             short* __restrict__ vt) {
  __shared__ short xs[2][32 * 64];
  __shared__ short wl[2][192 * 64];
  const int tid = threadIdx.x;
  const int m0 = blockIdx.x * 32;
  const int lane = tid & 63;
  const int wid = tid >> 6;             // 0..3
  const int g16 = lane >> 4, l16 = lane & 15;
  const int row0 = (wid & 1) * 16;      // wave's 16 rows
  const int nc0 = (wid >> 1) * 96;      // wave's 96 output cols

  f32x4 acc[6];
  #pragma unroll
  for (int i = 0; i < 6; ++i) acc[i] = (f32x4){0.f, 0.f, 0.f, 0.f};

  const int xr = tid >> 4;              // 0..15
  const int xc4 = (tid & 15) * 4;
  const int xsw = xc4 ^ ((xr & 7) << 3);
  const int wr = tid >> 3;              // 0..31
  const int wc8 = (tid & 7) * 8;
  const int wsw = wc8 ^ ((wr & 7) << 3);
  const int fsw = (l16 & 7) << 3;

  float4 xA0, xA1, xB0, xB1;
  s16x8 wA0, wA1, wA2, wA3, wA4, wA5;
  s16x8 wB0, wB1, wB2, wB3, wB4, wB5;

#define QKV_LOAD(S, kc) do { \
    x##S##0 = *(const float4*)&x[(size_t)(m0 + xr) * C + (kc) + xc4]; \
    x##S##1 = *(const float4*)&x[(size_t)(m0 + xr + 16) * C + (kc) + xc4]; \
    w##S##0 = *(const s16x8*)&wt[(wr +   0) * C + (kc) + wc8]; \
    w##S##1 = *(const s16x8*)&wt[(wr +  32) * C + (kc) + wc8]; \
    w##S##2 = *(const s16x8*)&wt[(wr +  64) * C + (kc) + wc8]; \
    w##S##3 = *(const s16x8*)&wt[(wr +  96) * C + (kc) + wc8]; \
    w##S##4 = *(const s16x8*)&wt[(wr + 128) * C + (kc) + wc8]; \
    w##S##5 = *(const s16x8*)&wt[(wr + 160) * C + (kc) + wc8]; \
  } while (0)

#define QKV_STORE(S, buf) do { \
    s16x4 h0 = { f2bf((x##S##0).x), f2bf((x##S##0).y), f2bf((x##S##0).z), f2bf((x##S##0).w) }; \
    s16x4 h1 = { f2bf((x##S##1).x), f2bf((x##S##1).y), f2bf((x##S##1).z), f2bf((x##S##1).w) }; \
    *(s16x4*)&xs[buf][xr * 64 + xsw] = h0; \
    *(s16x4*)&xs[buf][(xr + 16) * 64 + xsw] = h1; \
    *(s16x8*)&wl[buf][(wr +   0) * 64 + wsw] = w##S##0; \
    *(s16x8*)&wl[buf][(wr +  32) * 64 + wsw] = w##S##1; \
    *(s16x8*)&wl[buf][(wr +  64) * 64 + wsw] = w##S##2; \
    *(s16x8*)&wl[buf][(wr +  96) * 64 + wsw] = w##S##3; \
    *(s16x8*)&wl[buf][(wr + 128) * 64 + wsw] = w##S##4; \
    *(s16x8*)&wl[buf][(wr + 160) * 64 + wsw] = w##S##5; \
  } while (0)

#define QKV_COMPUTE(buf) do { \
    _Pragma("unroll") \
    for (int ks = 0; ks < 2; ++ks) { \
      bf16x8 a = *(const bf16x8*)&xs[buf][(row0 + l16) * 64 + ((ks * 32 + g16 * 8) ^ fsw)]; \
      _Pragma("unroll") \
      for (int nt = 0; nt < 6; ++nt) { \
        bf16x8 bfr = *(const bf16x8*)&wl[buf][(nc0 + nt * 16 + l16) * 64 + ((ks * 32 + g16 * 8) ^ fsw)]; \
        acc[nt] = __builtin_amdgcn_mfma_f32_16x16x32_bf16(a, bfr, acc[nt], 0, 0, 0); \
      } \
    } \
  } while (0)

  QKV_LOAD(A, 0);
  QKV_STORE(A, 0);       // waits on A loads (first tile, unavoidable)
  QKV_LOAD(B, 64);       // in flight across the barrier
  __syncthreads();

  #pragma unroll 1
  for (int ii = 0; ii < 8; ++ii) {
    // even iter: compute buf0 (=2ii); B holds 2ii+1
    if (ii < 7) QKV_LOAD(A, (2 * ii + 2) * 64);
    QKV_STORE(B, 1);
    QKV_COMPUTE(0);
    __syncthreads();
    // odd iter: compute buf1 (=2ii+1); A holds 2ii+2
    if (ii < 7) {
      QKV_LOAD(B, (2 * ii + 3) * 64);
      QKV_STORE(A, 0);
    }
    QKV_COMPUTE(1);
    if (ii < 7) __syncthreads();
  }
#undef QKV_LOAD
#undef QKV_STORE
#undef QKV_COMPUTE

  const int r0 = row0 + g16 * 4;
  #pragma unroll
  for (int nt = 0; nt < 6; ++nt) {
    const int nglob = nc0 + nt * 16;
    const int which = nglob >> 6;            // 0=q 1=k 2=v
    const int col = (nglob & 63) + l16;
    #pragma unroll
    for (int j = 0; j < 4; ++j) {
      const int tg = m0 + r0 + j;
      const short val = f2bf(acc[nt][j]);
      if (which == 0)      qb[tg * H + col] = val;
      else if (which == 1) kb[tg * H + col] = val;
      else {
        const int b = tg >> 11, tl = tg & (T - 1);
        vt[((b << 6) + col) * T + tl] = val;
      }
    }
  }
}

// ---------------- Kernel 2: flash attention, 8-wave split, defer-max -------
// Swapped operands: S = mfma(K,Q) so lane l16 = q; softmax lane-local.
// Defer-max: cross-lane shuffles + O/L rescale only when local max exceeds
// m + 7 (log2 domain). Per-lane partial L, reduced once at wave end.
// K regs double-buffered; V issued before softmax.
__global__ __launch_bounds__(512, 4) void k_attn(const short* __restrict__ qb,
                                                 const short* __restrict__ kb,
                                                 const short* __restrict__ vt,
                                                 const float* __restrict__ cvp,
                                                 float* __restrict__ out) {
  __shared__ short plds[8][2][16][40];
  __shared__ float mw[8][16];
  __shared__ float Lw[8][16];
  __shared__ float Ow[8][16][68];
  const int blk = blockIdx.x;
  const int b = blk & 7;                  // batch-interleaved, heavy-first
  const int t = 127 - (blk >> 3);
  const int q0 = t << 4;
  const int tid = threadIdx.x;
  const int wid = tid >> 6;               // 0..7
  const int lane = tid & 63;
  const int g16 = lane >> 4, l16 = lane & 15;
  const float cv = cvp[0];
  const float SCL = 0.125f * 1.44269504f; // 1/sqrt(64) * log2(e)

  const int nit = (q0 + 16 + 31) >> 5;    // 32-col iterations (causal)
  const int npw = (nit + 7) >> 3;
  const int lo = wid * npw;
  const int hi = (lo + npw < nit) ? lo + npw : nit;

  const short* qp = qb + ((size_t)(b << 11) + q0 + l16) * H + g16 * 8;
  bf16x8 qf0 = *(const bf16x8*)qp;
  bf16x8 qf1 = *(const bf16x8*)(qp + 32);
  const int qg = q0 + l16;

  float m = -3e38f, L = 0.f;              // L = per-lane partial
  f32x4 O[4];
  #pragma unroll
  for (int t4 = 0; t4 < 4; ++t4) O[t4] = (f32x4){0.f, 0.f, 0.f, 0.f};

  if (lo < hi) {
    const short* kp = kb + ((size_t)(b << 11) + lo * 32 + l16) * H + g16 * 8;
    const short* vp = vt + ((size_t)(b << 6) + l16) * T + lo * 32 + g16 * 8;
    bf16x8 kc0 = *(const bf16x8*)kp;
    bf16x8 kc1 = *(const bf16x8*)(kp + 32);
    bf16x8 kc2 = *(const bf16x8*)(kp + 16 * H);
    bf16x8 kc3 = *(const bf16x8*)(kp + 16 * H + 32);
    kp += 32 * H;

    for (int it = lo; it < hi; ++it) {
      bf16x8 kn0, kn1, kn2, kn3;
      const bool more = (it + 1 < hi);
      if (more) {                         // prefetch next K tile
        kn0 = *(const bf16x8*)kp;
        kn1 = *(const bf16x8*)(kp + 32);
        kn2 = *(const bf16x8*)(kp + 16 * H);
        kn3 = *(const bf16x8*)(kp + 16 * H + 32);
      }
      // V for current iter, issued before softmax
      bf16x8 v0 = *(const bf16x8*)vp;
      bf16x8 v1 = *(const bf16x8*)(vp + 16 * T);
      bf16x8 v2 = *(const bf16x8*)(vp + 32 * T);
      bf16x8 v3 = *(const bf16x8*)(vp + 48 * T);

      f32x4 s0 = {0.f,0.f,0.f,0.f}, s1 = {0.f,0.f,0.f,0.f};
      s0 = __builtin_amdgcn_mfma_f32_16x16x32_bf16(kc0, qf0, s0, 0, 0, 0);
      s0 = __builtin_amdgcn_mfma_f32_16x16x32_bf16(kc1, qf1, s0, 0, 0, 0);
      s1 = __builtin_amdgcn_mfma_f32_16x16x32_bf16(kc2, qf0, s1, 0, 0, 0);
      s1 = __builtin_amdgcn_mfma_f32_16x16x32_bf16(kc3, qf1, s1, 0, 0, 0);

      const int kv0 = it << 5;
      const int kvb = kv0 + g16 * 4;
      const bool diag = (kv0 + 31 > q0);  // tile straddles the causal edge
      float sv[8];
      if (diag) {
        #pragma unroll
        for (int r = 0; r < 8; ++r) {
          const int kvg = kvb + ((r >> 2) << 4) + (r & 3);
          const float s = ((r < 4) ? s0[r] : s1[r - 4]) * SCL;
          sv[r] = (kvg <= qg) ? s : -1e30f;
        }
      } else {
        #pragma unroll
        for (int r = 0; r < 8; ++r)
          sv[r] = ((r < 4) ? s0[r] : s1[r - 4]) * SCL;
      }

      float pmax = fmaxf(fmaxf(fmaxf(sv[0], sv[1]), fmaxf(sv[2], sv[3])),
                         fmaxf(fmaxf(sv[4], sv[5]), fmaxf(sv[6], sv[7])));
      if (!__all(pmax <= m + 7.f)) {      // slow path: true max + rescale
        float v = pmax;
        v = fmaxf(v, __shfl_xor(v, 16, 64));
        v = fmaxf(v, __shfl_xor(v, 32, 64));
        const float mn = fmaxf(m, v);
        const float al = exp2f(m - mn);
        m = mn;
        L *= al;
        #pragma unroll
        for (int t4 = 0; t4 < 4; ++t4) O[t4] *= al;
      }

      float p[8];
      #pragma unroll
      for (int r = 0; r < 8; ++r) {
        const int kvg = kvb + ((r >> 2) << 4) + (r & 3);
        const float sp = fminf(fmaxf((float)(kvg + 1) * (1.f / 2048.f) + cv, 0.f), 1.f);
        p[r] = exp2f(sv[r] - m) * sp;
      }
      if (diag) {                         // re-mask (guards all-masked rows)
        #pragma unroll
        for (int r = 0; r < 8; ++r) {
          const int kvg = kvb + ((r >> 2) << 4) + (r & 3);
          p[r] = (kvg <= qg) ? p[r] : 0.f;
        }
      }
      L += ((p[0] + p[1]) + (p[2] + p[3])) + ((p[4] + p[5]) + (p[6] + p[7]));

      short (*pl)[40] = plds[wid][it & 1];
      #pragma unroll
      for (int r = 0; r < 8; r += 2) {
        union { float f; unsigned u; } a0, a1;
        a0.f = p[r]; a1.f = p[r + 1];
        const unsigned pk = (a0.u >> 16) | (a1.u & 0xffff0000u);
        *(unsigned*)&pl[l16][((r >> 2) << 4) + g16 * 4 + (r & 3)] = pk;
      }
      bf16x8 pa = *(const bf16x8*)&pl[l16][g16 * 8];
      O[0] = __builtin_amdgcn_mfma_f32_16x16x32_bf16(v0, pa, O[0], 0, 0, 0);
      O[1] = __builtin_amdgcn_mfma_f32_16x16x32_bf16(v1, pa, O[1], 0, 0, 0);
      O[2] = __builtin_amdgcn_mfma_f32_16x16x32_bf16(v2, pa, O[2], 0, 0, 0);
      O[3] = __builtin_amdgcn_mfma_f32_16x16x32_bf16(v3, pa, O[3], 0, 0, 0);

      if (more) { kc0 = kn0; kc1 = kn1; kc2 = kn2; kc3 = kn3; }
      kp += 32 * H;
      vp += 32;
    }
  }

  // ---- per-wave partials ----
  float Lr = L;
  Lr += __shfl_xor(Lr, 16, 64);
  Lr += __shfl_xor(Lr, 32, 64);
  if (g16 == 0) { mw[wid][l16] = m; Lw[wid][l16] = Lr; }
  #pragma unroll
  for (int t4 = 0; t4 < 4; ++t4)
    *(f32x4*)&Ow[wid][l16][t4 * 16 + g16 * 4] = O[t4];
  __syncthreads();

  // ---- merge 8 partials: thread -> (row, 4 cols) ----
  if (tid < 256) {
    const int r = tid >> 4;
    const int c4 = (tid & 15) << 2;
    float Mx = -3e38f;
    #pragma unroll
    for (int w = 0; w < 8; ++w) Mx = fmaxf(Mx, mw[w][r]);
    float f[8], Ls = 0.f;
    #pragma unroll
    for (int w = 0; w < 8; ++w) {
      f[w] = exp2f(mw[w][r] - Mx);
      Ls += Lw[w][r] * f[w];
    }
    f32x4 o = (f32x4){0.f, 0.f, 0.f, 0.f};
    #pragma unroll
    for (int w = 0; w < 8; ++w) {
      f32x4 ow = *(const f32x4*)&Ow[w][r][c4];
      o += ow * f[w];
    }
    o *= 1.f / (Ls + 1e-30f);
    *(f32x4*)&out[(size_t)((b << 11) + q0 + r) * H + c4] = o;
  }
}

extern "C" void kernel_launch(void* const* d_in, const int* in_sizes, int n_in,
                              void* d_out, int out_size, void* d_ws, size_t ws_size,
                              hipStream_t stream) {
  const float* x  = (const float*)d_in[0];
  const float* Wq = (const float*)d_in[1];
  const float* Wk = (const float*)d_in[2];
  const float* Wv = (const float*)d_in[3];
  const float* cv = (const float*)d_in[4];
  float* out = (float*)d_out;

  char* ws = (char*)d_ws;
  short* qb = (short*)(ws);                              // 2 MB
  short* kb = (short*)(ws + (size_t)M * H * 2);          // 2 MB
  short* vt = (short*)(ws + (size_t)2 * M * H * 2);      // 2 MB
  short* wt = (short*)(ws + (size_t)3 * M * H * 2);      // 384 KB

  hipLaunchKernelGGL(k_wt, dim3(3 * H * C / 256), dim3(256), 0, stream, Wq, Wk, Wv, wt);
  hipLaunchKernelGGL(k_qkv, dim3(M / 32), dim3(256), 0, stream, x, wt, qb, kb, vt);
  hipLaunchKernelGGL(k_attn, dim3(BSZ * T / 16), dim3(512), 0, stream, qb, kb, vt, cv, out);
}